// Round 8
// baseline (220.836 us; speedup 1.0000x reference)
//
#include <hip/hip_runtime.h>

// MultiHeadAttention_137438953529 on gfx950.
// B=8, S=1024, E=1024, H=16, D=64.  The reference's reshapes are flat
// reinterpretations => attention mixes only groups of 8 consecutive rows of
// the (8192 x 1024) projected matrices, per 64-wide head slice.
//
// R8: A-operand fully out of LDS and out of the barrier.  R1-R7 all paid a
// per-iter A-tax (stage+cvt+ds_write+ds_read+lgkm inside the fence) and sat
// at 370-450 TF.  Now each wave loads its OWN A-fragments straight from
// global (8x dwordx4 f32, L1/L2-hot), 1 iter ahead into a single 32-reg aR,
// cvt_pk'd to bf16 right before the MFMAs.  LDS = B only (2x8KB).  Fence =
// vmcnt(8)+barrier (drains 2 B-glds, leaves 8 A-loads in flight; STAGE_B
// pinned before ISSUE_A so the counting is exact).  ~155 unified regs at
// (256,3): no spill.  Kept verbatim: XCD-family decode, B source-side chunk
// XOR (0 conflicts), m97 epilogue, cvt_w, attn.

typedef __attribute__((ext_vector_type(4))) float f32x4;
typedef __attribute__((ext_vector_type(8))) short bf16x8;   // MFMA A/B fragment
typedef __attribute__((ext_vector_type(8))) unsigned short u16x8;

#define WAIT_VM(n) asm volatile("s_waitcnt vmcnt(" #n ")" ::: "memory")

__device__ __forceinline__ unsigned short f2bf(float f) {
  unsigned int u = __builtin_bit_cast(unsigned int, f);
  u += 0x7fffu + ((u >> 16) & 1u);          // round-to-nearest-even
  return (unsigned short)(u >> 16);
}
__device__ __forceinline__ float bf2f(unsigned short b) {
  return __builtin_bit_cast(float, ((unsigned int)b) << 16);
}
__device__ __forceinline__ u16x8 pack8(f32x4 a, f32x4 b) {
  u16x8 o;
  o[0] = f2bf(a[0]); o[1] = f2bf(a[1]); o[2] = f2bf(a[2]); o[3] = f2bf(a[3]);
  o[4] = f2bf(b[0]); o[5] = f2bf(b[1]); o[6] = f2bf(b[2]); o[7] = f2bf(b[3]);
  return o;
}
// 8x f32 -> 8x bf16 via packed cvt (RNE), as MFMA fragment
__device__ __forceinline__ bf16x8 cvt8(f32x4 a, f32x4 b) {
  union { unsigned int u[4]; bf16x8 v; } r;
  asm("v_cvt_pk_bf16_f32 %0, %1, %2" : "=v"(r.u[0]) : "v"(a[0]), "v"(a[1]));
  asm("v_cvt_pk_bf16_f32 %0, %1, %2" : "=v"(r.u[1]) : "v"(a[2]), "v"(a[3]));
  asm("v_cvt_pk_bf16_f32 %0, %1, %2" : "=v"(r.u[2]) : "v"(b[0]), "v"(b[1]));
  asm("v_cvt_pk_bf16_f32 %0, %1, %2" : "=v"(r.u[3]) : "v"(b[2]), "v"(b[3]));
  return r.v;
}

__device__ __forceinline__ void gload_lds16(const void* g, void* l) {
  __builtin_amdgcn_global_load_lds(
      (const __attribute__((address_space(1))) unsigned int*)g,
      (__attribute__((address_space(3))) unsigned int*)l, 16, 0, 0);
}

// --------------------------------------------------- W -> bf16 (linear layout)
__global__ __launch_bounds__(256) void cvt_w(const float* __restrict__ Wq,
                                             const float* __restrict__ Wk,
                                             const float* __restrict__ Wv,
                                             unsigned short* __restrict__ Wb) {
  int i = blockIdx.x * 256 + threadIdx.x;     // 0 .. 393216 (3 * 131072 chunks of 8)
  int proj = i >> 17;
  int local = i & 131071;
  const float* src = (proj == 0 ? Wq : proj == 1 ? Wk : Wv) + (size_t)local * 8;
  f32x4 a = reinterpret_cast<const f32x4*>(src)[0];
  f32x4 b = reinterpret_cast<const f32x4*>(src)[1];
  *reinterpret_cast<u16x8*>(Wb + (size_t)proj * 1048576 + (size_t)local * 8) = pack8(a, b);
}

// ------------------------------------------------------------ QKV projection
// C[8192x1024] = X @ W^T + bias per proj.  BM=BN=128, BK=32, 256 threads,
// 4 waves (2x2), per-wave 64x64 (4x4 frags of 16x16x32 bf16 MFMA), 32 K-iters.
__global__ __launch_bounds__(256, 3) void gemm8(
    const float* __restrict__ Xq, const float* __restrict__ Xk, const float* __restrict__ Xv,
    const unsigned short* __restrict__ Wb,
    const float* __restrict__ bq, const float* __restrict__ bk, const float* __restrict__ bv,
    unsigned short* __restrict__ QKV) {
  // XCD-family decode: XCD c (dispatch round-robin d%8) owns x in [8c,8c+8);
  // consecutive-in-time blocks on one XCD share x (X panel L2-resident) and
  // sweep y (W bf16 6 MB total, L2/L3-resident).
  const int d = blockIdx.x;
  const int xcd = d & 7;
  const int k5 = d >> 3;
  const int y = k5 & 7;
  const int rest = k5 >> 3;       // 0..23
  const int proj = rest >> 3;     // 0..2
  const int xg = rest & 7;
  const int x = xcd * 8 + xg;     // 0..63

  const float* X = (proj == 0) ? Xq : (proj == 1) ? Xk : Xv;
  const float* bias = (proj == 0) ? bq : (proj == 1) ? bk : bv;
  const unsigned short* W = Wb + (size_t)proj * 1048576;
  unsigned short* O = QKV + (size_t)proj * 8388608;

  const int rowBase = x * 128;
  const int colBase = y * 128;

  __shared__ alignas(16) unsigned short Bs[2][4096];   // [128 rows][32 k] bf16, chunk-XOR'd

  const int t = threadIdx.x;
  const int l = t & 63;
  const int w = t >> 6;
  const int wr = w >> 1, wc = w & 1;

  f32x4 acc[4][4];
#pragma unroll
  for (int m = 0; m < 4; ++m)
#pragma unroll
    for (int n = 0; n < 4; ++n) acc[m][n] = f32x4{0.f, 0.f, 0.f, 0.f};

  // B fragment read offsets (ushort units): logical chunk g of row r lives at
  // physical chunk g ^ ((r>>1)&3)
  int boff[4];
#pragma unroll
  for (int n = 0; n < 4; ++n) {
    const int row = wc * 64 + n * 16 + (l & 15);
    boff[n] = row * 32 + (((l >> 4) ^ ((row >> 1) & 3)) * 8);
  }

  // A: rolling per-frag global pointers.  Frag m, this lane: row
  // rowBase + wr*64 + m*16 + (l&15), k-slot (l>>4)*8 (8 f32 = 2 dwordx4).
  // Rows are reused across the 4 (l>>4) lane groups + the wc-partner wave
  // within the iter -> L1-resident.
  const float* aPm[4];
#pragma unroll
  for (int m = 0; m < 4; ++m)
    aPm[m] = X + (size_t)(rowBase + wr * 64 + m * 16 + (l & 15)) * 1024 + (l >> 4) * 8;

  f32x4 aR[8];
#define ISSUE_A()                                                                 \
  {                                                                               \
    _Pragma("unroll") for (int m = 0; m < 4; ++m) {                               \
      aR[2 * m]     = *reinterpret_cast<const f32x4*>(aPm[m]);                    \
      aR[2 * m + 1] = *reinterpret_cast<const f32x4*>(aPm[m] + 4);                \
      aPm[m] += 32;                                                               \
    }                                                                             \
  }

  // B staging: thread t, call j: linear dest byte o = (j*4+w)*1024 + l*16;
  // row = o>>6, phys chunk = l&3; source chunk = (l&3) ^ ((row>>1)&3)
  const int srow0 = w * 16 + (l >> 2);
  const int sc = l & 3;
#define STAGE_B(dst, kt)                                                          \
  {                                                                               \
    _Pragma("unroll") for (int j = 0; j < 2; ++j) {                               \
      const int row = j * 64 + srow0;                                             \
      const int cp = sc ^ ((row >> 1) & 3);                                       \
      gload_lds16(W + (size_t)(colBase + row) * 1024 + (kt) * 32 + cp * 8,        \
                  (dst) + (j * 4 + w) * 512 + l * 8);                             \
    }                                                                             \
  }

#define FENCE                                                                     \
  WAIT_VM(8);                                                                     \
  __builtin_amdgcn_sched_barrier(0);                                              \
  __builtin_amdgcn_s_barrier();                                                   \
  __builtin_amdgcn_sched_barrier(0)

  // ---- prologue: B(0) -> Bs[0]; A(0) -> aR (stays in flight past the fence)
  STAGE_B(&Bs[0][0], 0);
  __builtin_amdgcn_sched_barrier(0);    // pin: glds older than A loads
  ISSUE_A();                            // tile 0
  FENCE;                                // vm(8): drains glds(0), leaves A(0)

  // ---- main loop: iter kt computes tile kt; stages B(kt+1); prefetches A(kt+1)
  for (int kt = 0; kt < 32; ++kt) {
    const int cb = kt & 1;
    if (kt + 1 < 32) {
      STAGE_B(&Bs[cb ^ 1][0], kt + 1);
      __builtin_amdgcn_sched_barrier(0);  // pin: glds oldest among this iter's VMEM
    }
    // B fragments (lgkm auto-waited before MFMA use)
    bf16x8 bfr[4];
#pragma unroll
    for (int n = 0; n < 4; ++n)
      bfr[n] = *reinterpret_cast<const bf16x8*>(&Bs[cb][boff[n]]);
    // A fragments: cvt consumes aR (auto vmcnt), then refill aR for kt+1
    bf16x8 af[4];
#pragma unroll
    for (int m = 0; m < 4; ++m) af[m] = cvt8(aR[2 * m], aR[2 * m + 1]);
    if (kt + 1 < 32) ISSUE_A();
    __builtin_amdgcn_s_setprio(1);
#pragma unroll
    for (int m = 0; m < 4; ++m)
#pragma unroll
      for (int n = 0; n < 4; ++n)
        acc[m][n] = __builtin_amdgcn_mfma_f32_16x16x32_bf16(af[m], bfr[n], acc[m][n], 0, 0, 0);
    __builtin_amdgcn_s_setprio(0);
    if (kt + 1 < 32) { FENCE; }   // vm(8): drains glds(kt+1), leaves A(kt+1)
  }

  // ---- epilogue: C/D layout col=lane&15, row=(lane>>4)*4+reg
#pragma unroll
  for (int n = 0; n < 4; ++n) {
    const int col = colBase + wc * 64 + n * 16 + (l & 15);
    const float bn = bias[col];
#pragma unroll
    for (int m = 0; m < 4; ++m) {
      const int row0 = rowBase + wr * 64 + m * 16 + (l >> 4) * 4;
#pragma unroll
      for (int j = 0; j < 4; ++j)
        O[(size_t)(row0 + j) * 1024 + col] = f2bf(acc[m][n][j] + bn);
    }
  }
#undef ISSUE_A
#undef STAGE_B
#undef FENCE
}

// ------------------------------------------------------------------ attention
// thread = (n group, head h, d-quarter dq, row-half rh): 4 q-rows x 16 d-cols
// of the 8-key attention; QK partial dots reduced across 4 dq lanes.
__global__ __launch_bounds__(256) void attn_kernel(const unsigned short* __restrict__ QKV,
                                                   float* __restrict__ out) {
  const int t = threadIdx.x;
  const int lane = t & 63;
  const int dq = lane & 3;
  const int h = (lane >> 2) & 15;
  const int rh = (t >> 6) & 1;
  const int n = blockIdx.x * 2 + (t >> 7);

  const unsigned short* Q = QKV;
  const unsigned short* K = QKV + (size_t)8388608;
  const unsigned short* V = QKV + (size_t)16777216;
  const size_t gbase = (size_t)n * 8192;
  const int coff = h * 64 + dq * 16;

  float q[4][16];
#pragma unroll
  for (int r = 0; r < 4; ++r) {
    const unsigned short* qp = Q + gbase + (size_t)(rh * 4 + r) * 1024 + coff;
    u16x8 a = *reinterpret_cast<const u16x8*>(qp);
    u16x8 b = *reinterpret_cast<const u16x8*>(qp + 8);
#pragma unroll
    for (int c = 0; c < 8; ++c) { q[r][c] = bf2f(a[c]); q[r][8 + c] = bf2f(b[c]); }
  }

  float s[4][8];
#pragma unroll
  for (int r = 0; r < 4; ++r)
#pragma unroll
    for (int j = 0; j < 8; ++j) s[r][j] = 0.f;

#pragma unroll
  for (int j = 0; j < 8; ++j) {
    const unsigned short* kp = K + gbase + (size_t)j * 1024 + coff;
    u16x8 a = *reinterpret_cast<const u16x8*>(kp);
    u16x8 b = *reinterpret_cast<const u16x8*>(kp + 8);
    float kv[16];
#pragma unroll
    for (int c = 0; c < 8; ++c) { kv[c] = bf2f(a[c]); kv[8 + c] = bf2f(b[c]); }
#pragma unroll
    for (int r = 0; r < 4; ++r) {
      float acc = 0.f;
#pragma unroll
      for (int c = 0; c < 16; ++c) acc += q[r][c] * kv[c];
      s[r][j] += acc;
    }
  }

#pragma unroll
  for (int r = 0; r < 4; ++r)
#pragma unroll
    for (int j = 0; j < 8; ++j) {
      float v = s[r][j];
      v += __shfl_xor(v, 1, 64);
      v += __shfl_xor(v, 2, 64);
      s[r][j] = v;
    }

  float p[4][8];
#pragma unroll
  for (int r = 0; r < 4; ++r) {
    float mx = s[r][0];
#pragma unroll
    for (int j = 1; j < 8; ++j) mx = fmaxf(mx, s[r][j]);
    float sum = 0.f;
#pragma unroll
    for (int j = 0; j < 8; ++j) {
      float e = __expf(0.125f * (s[r][j] - mx));  // SCALE = 1/sqrt(64)
      p[r][j] = e;
      sum += e;
    }
    float inv = 1.f / sum;
#pragma unroll
    for (int j = 0; j < 8; ++j) p[r][j] *= inv;
  }

  float o[4][16];
#pragma unroll
  for (int r = 0; r < 4; ++r)
#pragma unroll
    for (int c = 0; c < 16; ++c) o[r][c] = 0.f;

#pragma unroll
  for (int j = 0; j < 8; ++j) {
    const unsigned short* vp = V + gbase + (size_t)j * 1024 + coff;
    u16x8 a = *reinterpret_cast<const u16x8*>(vp);
    u16x8 b = *reinterpret_cast<const u16x8*>(vp + 8);
    float vv[16];
#pragma unroll
    for (int c = 0; c < 8; ++c) { vv[c] = bf2f(a[c]); vv[8 + c] = bf2f(b[c]); }
#pragma unroll
    for (int r = 0; r < 4; ++r)
#pragma unroll
      for (int c = 0; c < 16; ++c) o[r][c] += p[r][j] * vv[c];
  }

#pragma unroll
  for (int r = 0; r < 4; ++r) {
    float* op = out + gbase + (size_t)(rh * 4 + r) * 1024 + coff;
    f32x4 v0 = {o[r][0], o[r][1], o[r][2], o[r][3]};
    f32x4 v1 = {o[r][4], o[r][5], o[r][6], o[r][7]};
    f32x4 v2 = {o[r][8], o[r][9], o[r][10], o[r][11]};
    f32x4 v3 = {o[r][12], o[r][13], o[r][14], o[r][15]};
    reinterpret_cast<f32x4*>(op)[0] = v0;
    reinterpret_cast<f32x4*>(op)[1] = v1;
    reinterpret_cast<f32x4*>(op)[2] = v2;
    reinterpret_cast<f32x4*>(op)[3] = v3;
  }
}

// ------------------------------------------------------------------- launch
extern "C" void kernel_launch(void* const* d_in, const int* in_sizes, int n_in,
                              void* d_out, int out_size, void* d_ws, size_t ws_size,
                              hipStream_t stream) {
  const float* Xq = (const float*)d_in[0];
  const float* Xk = (const float*)d_in[1];
  const float* Xv = (const float*)d_in[2];
  const float* Wq = (const float*)d_in[3];
  const float* bq = (const float*)d_in[4];
  const float* Wk = (const float*)d_in[5];
  const float* bk = (const float*)d_in[6];
  const float* Wv = (const float*)d_in[7];
  const float* bv = (const float*)d_in[8];

  unsigned short* ws = (unsigned short*)d_ws;
  unsigned short* Wb = ws;                              // 3 x 1M bf16 (6 MB), linear
  unsigned short* QKV = ws + (size_t)3 * 1024 * 1024;   // 3 x 8M bf16 (48 MB)

  cvt_w<<<1536, 256, 0, stream>>>(Wq, Wk, Wv, Wb);
  gemm8<<<1536, 256, 0, stream>>>(Xq, Xk, Xv, Wb, bq, bk, bv, QKV);
  attn_kernel<<<512, 256, 0, stream>>>(QKV, (float*)d_out);
}

// Round 9
// 168.277 us; speedup vs baseline: 1.3123x; 1.3123x over previous
//
#include <hip/hip_runtime.h>

// MultiHeadAttention_137438953529 on gfx950.
// B=8, S=1024, E=1024, H=16, D=64.  The reference's reshapes are flat
// reinterpretations => attention mixes only groups of 8 consecutive rows of
// the (8192 x 1024) projected matrices, per 64-wide head slice.
//
// R9: 8-phase-template port (T3+T4+T5+T2).  R1-R8 evidence: every 2-barrier
// structure caps at 14-18% MfmaUtil (m233: stage+fence = ~72% of the period).
// New GEMM: BM=256 BN=128 BK=64, 512 thr / 8 waves (4Mx2N), 64x64 per wave,
// grid 768 = exactly 3 rounds; LDS 96KB dbuf; 4 phases per K-tile, each
// {ds_reads + one staging cluster; bar; setprio+8 MFMA; bar}; ONE counted
// vmcnt(8) per K-tile (drains only the 2 B-glds; 8 A-globals stay in flight
// across barriers); A staged f32->reg (1 iter ahead) -> cvt_pk -> swizzled
// ds_write at P3 (~7 phases of slack).  Chunk-XOR c^(row&7) everywhere.

typedef __attribute__((ext_vector_type(4))) float f32x4;
typedef __attribute__((ext_vector_type(8))) short bf16x8;   // MFMA A/B fragment
typedef __attribute__((ext_vector_type(8))) unsigned short u16x8;

#define WAIT_LGKM0 asm volatile("s_waitcnt lgkmcnt(0)" ::: "memory")
#define WAIT_VM(n) asm volatile("s_waitcnt vmcnt(" #n ")" ::: "memory")
#define SCHED0 __builtin_amdgcn_sched_barrier(0)
#define BARRIER __builtin_amdgcn_s_barrier()

__device__ __forceinline__ unsigned short f2bf(float f) {
  unsigned int u = __builtin_bit_cast(unsigned int, f);
  u += 0x7fffu + ((u >> 16) & 1u);          // round-to-nearest-even
  return (unsigned short)(u >> 16);
}
__device__ __forceinline__ float bf2f(unsigned short b) {
  return __builtin_bit_cast(float, ((unsigned int)b) << 16);
}
__device__ __forceinline__ u16x8 pack8(f32x4 a, f32x4 b) {
  u16x8 o;
  o[0] = f2bf(a[0]); o[1] = f2bf(a[1]); o[2] = f2bf(a[2]); o[3] = f2bf(a[3]);
  o[4] = f2bf(b[0]); o[5] = f2bf(b[1]); o[6] = f2bf(b[2]); o[7] = f2bf(b[3]);
  return o;
}
// 8x f32 -> 8x bf16 via packed cvt (RNE)
__device__ __forceinline__ u16x8 cvt8(f32x4 a, f32x4 b) {
  union { unsigned int u[4]; u16x8 v; } r;
  asm("v_cvt_pk_bf16_f32 %0, %1, %2" : "=v"(r.u[0]) : "v"(a[0]), "v"(a[1]));
  asm("v_cvt_pk_bf16_f32 %0, %1, %2" : "=v"(r.u[1]) : "v"(a[2]), "v"(a[3]));
  asm("v_cvt_pk_bf16_f32 %0, %1, %2" : "=v"(r.u[2]) : "v"(b[0]), "v"(b[1]));
  asm("v_cvt_pk_bf16_f32 %0, %1, %2" : "=v"(r.u[3]) : "v"(b[2]), "v"(b[3]));
  return r.v;
}

__device__ __forceinline__ void gload_lds16(const void* g, void* l) {
  __builtin_amdgcn_global_load_lds(
      (const __attribute__((address_space(1))) unsigned int*)g,
      (__attribute__((address_space(3))) unsigned int*)l, 16, 0, 0);
}

// --------------------------------------------------- W -> bf16 (linear layout)
__global__ __launch_bounds__(256) void cvt_w(const float* __restrict__ Wq,
                                             const float* __restrict__ Wk,
                                             const float* __restrict__ Wv,
                                             unsigned short* __restrict__ Wb) {
  int i = blockIdx.x * 256 + threadIdx.x;     // 0 .. 393216 (3 * 131072 chunks of 8)
  int proj = i >> 17;
  int local = i & 131071;
  const float* src = (proj == 0 ? Wq : proj == 1 ? Wk : Wv) + (size_t)local * 8;
  f32x4 a = reinterpret_cast<const f32x4*>(src)[0];
  f32x4 b = reinterpret_cast<const f32x4*>(src)[1];
  *reinterpret_cast<u16x8*>(Wb + (size_t)proj * 1048576 + (size_t)local * 8) = pack8(a, b);
}

// ------------------------------------------------------------ QKV projection
// C[8192x1024] = X @ W^T + bias per proj.  BM=256 BN=128 BK=64, 512 threads,
// 8 waves (4Mx2N), per-wave 64x64 (4x4 frags of 16x16x32 bf16 MFMA, 2 k-halves),
// 16 K-tiles.  4 phases per K-tile (one per m-frag).
__global__ __launch_bounds__(512, 2) void gemm9(
    const float* __restrict__ Xq, const float* __restrict__ Xk, const float* __restrict__ Xv,
    const unsigned short* __restrict__ Wb,
    const float* __restrict__ bq, const float* __restrict__ bk, const float* __restrict__ bv,
    unsigned short* __restrict__ QKV) {
  // XCD decode: 768 blocks; xcd = d&7 owns x in [4c,4c+4) per proj; blocks on
  // one XCD sweep y with x held -> X panel L2-resident, W panel L2/L3.
  const int d = blockIdx.x;
  const int xcd = d & 7;
  const int r5 = d >> 3;          // 0..95
  const int y = r5 & 7;
  const int r2 = r5 >> 3;         // 0..11
  const int xg = r2 & 3;
  const int proj = r2 >> 2;       // 0..2
  const int x = xcd * 4 + xg;     // 0..31

  const float* X = (proj == 0) ? Xq : (proj == 1) ? Xk : Xv;
  const float* bias = (proj == 0) ? bq : (proj == 1) ? bk : bv;
  const unsigned short* W = Wb + (size_t)proj * 1048576;
  unsigned short* O = QKV + (size_t)proj * 8388608;

  const int rowBase = x * 256;
  const int colBase = y * 128;

  __shared__ alignas(16) unsigned short As[2][16384];  // [256 rows][64 k] bf16, XOR'd
  __shared__ alignas(16) unsigned short Bs[2][8192];   // [128 rows][64 k] bf16, XOR'd

  const int t = threadIdx.x;
  const int l = t & 63;
  const int w = t >> 6;           // 0..7
  const int wr = w >> 1;          // 0..3 (M quarter)
  const int wc = w & 1;           // 0..1 (N half)

  f32x4 acc[4][4];
#pragma unroll
  for (int m = 0; m < 4; ++m)
#pragma unroll
    for (int n = 0; n < 4; ++n) acc[m][n] = f32x4{0.f, 0.f, 0.f, 0.f};

  // B staging: 16KB via 2 glds/thread.  dest byte o=(j*8+w)*1024+l*16;
  // row=o>>7, phys chunk=l&7, src chunk = (l&7)^(row&7).
#define STAGE_B(dst, kt)                                                          \
  {                                                                               \
    _Pragma("unroll") for (int j = 0; j < 2; ++j) {                               \
      const int o = (j * 8 + w) * 1024 + l * 16;                                  \
      const int row = o >> 7;                                                     \
      const int cp = (l & 7) ^ (row & 7);                                         \
      gload_lds16(W + (size_t)(colBase + row) * 1024 + (kt) * 64 + cp * 8,        \
                  (char*)(dst) + o);                                              \
    }                                                                             \
  }

  // A global f32 loads: thread t covers row t>>1, k-half (t&1)*32 (8 f32x4).
#define LOAD_A(kt, R)                                                             \
  {                                                                               \
    const float* ap =                                                             \
        X + (size_t)(rowBase + (t >> 1)) * 1024 + (kt) * 64 + (t & 1) * 32;       \
    _Pragma("unroll") for (int i = 0; i < 8; ++i)                                 \
        R[i] = reinterpret_cast<const f32x4*>(ap)[i];                             \
  }

  // A cvt+swizzled ds_write: row r=t>>1, chunks 4h..4h+3 at phys (c)^(r&7).
#define CVT_WRITE_A(dst, R)                                                       \
  {                                                                               \
    const int r = t >> 1, hh = t & 1;                                             \
    unsigned short* ab = (dst) + r * 64;                                          \
    _Pragma("unroll") for (int i = 0; i < 4; ++i) {                               \
      const int pc = (4 * hh + i) ^ (r & 7);                                      \
      *reinterpret_cast<u16x8*>(ab + pc * 8) = cvt8(R[2 * i], R[2 * i + 1]);      \
    }                                                                             \
  }

  // A fragment reads for m-frag MM: chunks (l>>4) and 4+(l>>4), XOR row&7.
#define READ_A(AC, MM)                                                            \
  {                                                                               \
    const int arow = wr * 64 + (MM) * 16 + (l & 15);                              \
    const unsigned short* ab = (AC) + arow * 64;                                  \
    af0 = *reinterpret_cast<const bf16x8*>(ab + (((l >> 4) ^ (arow & 7)) * 8));   \
    af1 = *reinterpret_cast<const bf16x8*>(ab + (((4 + (l >> 4)) ^ (arow & 7)) * 8)); \
  }

#define MFMA8(MM)                                                                 \
  {                                                                               \
    __builtin_amdgcn_s_setprio(1);                                                \
    _Pragma("unroll") for (int n = 0; n < 4; ++n)                                 \
        acc[MM][n] = __builtin_amdgcn_mfma_f32_16x16x32_bf16(af0, bfr[n][0],      \
                                                             acc[MM][n], 0, 0, 0); \
    _Pragma("unroll") for (int n = 0; n < 4; ++n)                                 \
        acc[MM][n] = __builtin_amdgcn_mfma_f32_16x16x32_bf16(af1, bfr[n][1],      \
                                                             acc[MM][n], 0, 0, 0); \
    __builtin_amdgcn_s_setprio(0);                                                \
  }

  // One K-tile = 4 phases.  Computes tile KT from (AC,BC); stages B(KT+1) into
  // BO (P0, glds), A(KT+2) globals into NXT (P1), cvt+writes A(KT+1)=CUR into
  // AO (P3).  End-of-tile: lgkm0 + vmcnt(8) (drains glds, leaves A-globals).
#define ITER(KT, AC, BC, AO, BO, CUR, NXT)                                        \
  {                                                                               \
    /* ---- P0 */                                                                 \
    if ((KT) + 1 < 16) { STAGE_B(BO, (KT) + 1); }                                 \
    SCHED0;                                                                       \
    bf16x8 bfr[4][2];                                                             \
    _Pragma("unroll") for (int n = 0; n < 4; ++n) {                               \
      const int brow = wc * 64 + n * 16 + (l & 15);                               \
      const unsigned short* bb = (BC) + brow * 64;                                \
      bfr[n][0] = *reinterpret_cast<const bf16x8*>(bb + (((l >> 4) ^ (brow & 7)) * 8)); \
      bfr[n][1] = *reinterpret_cast<const bf16x8*>(bb + (((4 + (l >> 4)) ^ (brow & 7)) * 8)); \
    }                                                                             \
    bf16x8 af0, af1;                                                              \
    READ_A(AC, 0);                                                                \
    BARRIER;                                                                      \
    MFMA8(0);                                                                     \
    BARRIER; SCHED0;                                                              \
    /* ---- P1 */                                                                 \
    if ((KT) + 2 < 16) { LOAD_A((KT) + 2, NXT); }                                 \
    READ_A(AC, 1);                                                                \
    BARRIER;                                                                      \
    MFMA8(1);                                                                     \
    BARRIER; SCHED0;                                                              \
    /* ---- P2 */                                                                 \
    READ_A(AC, 2);                                                                \
    BARRIER;                                                                      \
    MFMA8(2);                                                                     \
    BARRIER; SCHED0;                                                              \
    /* ---- P3 */                                                                 \
    READ_A(AC, 3);                                                                \
    if ((KT) + 1 < 16) { CVT_WRITE_A(AO, CUR); }                                  \
    BARRIER;                                                                      \
    MFMA8(3);                                                                     \
    WAIT_LGKM0;                                                                   \
    if ((KT) + 2 < 16) { WAIT_VM(8); } else { WAIT_VM(0); }                       \
    SCHED0; BARRIER; SCHED0;                                                      \
  }

  f32x4 aRa[8], aRb[8];

  // ---- prologue: buf0 <- tile 0 (A via reg+cvt, B via glds); aRa <- A(1)
  LOAD_A(0, aRb);
  CVT_WRITE_A(&As[0][0], aRb);   // reg dep drains all 8 A(0) loads
  SCHED0;
  STAGE_B(&Bs[0][0], 0);         // 2 glds
  SCHED0;
  LOAD_A(1, aRa);                // 8 -> 10 outstanding
  WAIT_VM(8);                    // drain glds(0); leave A(1) in flight
  WAIT_LGKM0;
  SCHED0; BARRIER; SCHED0;

  // ---- main loop: 16 K-tiles, manual 2-step unroll (static bufs + reg pp)
  for (int kt = 0; kt < 16; kt += 2) {
    ITER(kt,     &As[0][0], &Bs[0][0], &As[1][0], &Bs[1][0], aRa, aRb);
    ITER(kt + 1, &As[1][0], &Bs[1][0], &As[0][0], &Bs[0][0], aRb, aRa);
  }

  // ---- epilogue: C/D layout col=lane&15, row=(lane>>4)*4+reg
#pragma unroll
  for (int n = 0; n < 4; ++n) {
    const int col = colBase + wc * 64 + n * 16 + (l & 15);
    const float bn = bias[col];
#pragma unroll
    for (int m = 0; m < 4; ++m) {
      const int row0 = rowBase + wr * 64 + m * 16 + (l >> 4) * 4;
#pragma unroll
      for (int j = 0; j < 4; ++j)
        O[(size_t)(row0 + j) * 1024 + col] = f2bf(acc[m][n][j] + bn);
    }
  }
#undef STAGE_B
#undef LOAD_A
#undef CVT_WRITE_A
#undef READ_A
#undef MFMA8
#undef ITER
}

// ------------------------------------------------------------------ attention
// thread = (n group, head h, d-quarter dq, row-half rh): 4 q-rows x 16 d-cols
// of the 8-key attention; QK partial dots reduced across 4 dq lanes.
__global__ __launch_bounds__(256) void attn_kernel(const unsigned short* __restrict__ QKV,
                                                   float* __restrict__ out) {
  const int t = threadIdx.x;
  const int lane = t & 63;
  const int dq = lane & 3;
  const int h = (lane >> 2) & 15;
  const int rh = (t >> 6) & 1;
  const int n = blockIdx.x * 2 + (t >> 7);

  const unsigned short* Q = QKV;
  const unsigned short* K = QKV + (size_t)8388608;
  const unsigned short* V = QKV + (size_t)16777216;
  const size_t gbase = (size_t)n * 8192;
  const int coff = h * 64 + dq * 16;

  float q[4][16];
#pragma unroll
  for (int r = 0; r < 4; ++r) {
    const unsigned short* qp = Q + gbase + (size_t)(rh * 4 + r) * 1024 + coff;
    u16x8 a = *reinterpret_cast<const u16x8*>(qp);
    u16x8 b = *reinterpret_cast<const u16x8*>(qp + 8);
#pragma unroll
    for (int c = 0; c < 8; ++c) { q[r][c] = bf2f(a[c]); q[r][8 + c] = bf2f(b[c]); }
  }

  float s[4][8];
#pragma unroll
  for (int r = 0; r < 4; ++r)
#pragma unroll
    for (int j = 0; j < 8; ++j) s[r][j] = 0.f;

#pragma unroll
  for (int j = 0; j < 8; ++j) {
    const unsigned short* kp = K + gbase + (size_t)j * 1024 + coff;
    u16x8 a = *reinterpret_cast<const u16x8*>(kp);
    u16x8 b = *reinterpret_cast<const u16x8*>(kp + 8);
    float kv[16];
#pragma unroll
    for (int c = 0; c < 8; ++c) { kv[c] = bf2f(a[c]); kv[8 + c] = bf2f(b[c]); }
#pragma unroll
    for (int r = 0; r < 4; ++r) {
      float acc = 0.f;
#pragma unroll
      for (int c = 0; c < 16; ++c) acc += q[r][c] * kv[c];
      s[r][j] += acc;
    }
  }

#pragma unroll
  for (int r = 0; r < 4; ++r)
#pragma unroll
    for (int j = 0; j < 8; ++j) {
      float v = s[r][j];
      v += __shfl_xor(v, 1, 64);
      v += __shfl_xor(v, 2, 64);
      s[r][j] = v;
    }

  float p[4][8];
#pragma unroll
  for (int r = 0; r < 4; ++r) {
    float mx = s[r][0];
#pragma unroll
    for (int j = 1; j < 8; ++j) mx = fmaxf(mx, s[r][j]);
    float sum = 0.f;
#pragma unroll
    for (int j = 0; j < 8; ++j) {
      float e = __expf(0.125f * (s[r][j] - mx));  // SCALE = 1/sqrt(64)
      p[r][j] = e;
      sum += e;
    }
    float inv = 1.f / sum;
#pragma unroll
    for (int j = 0; j < 8; ++j) p[r][j] *= inv;
  }

  float o[4][16];
#pragma unroll
  for (int r = 0; r < 4; ++r)
#pragma unroll
    for (int c = 0; c < 16; ++c) o[r][c] = 0.f;

#pragma unroll
  for (int j = 0; j < 8; ++j) {
    const unsigned short* vp = V + gbase + (size_t)j * 1024 + coff;
    u16x8 a = *reinterpret_cast<const u16x8*>(vp);
    u16x8 b = *reinterpret_cast<const u16x8*>(vp + 8);
    float vv[16];
#pragma unroll
    for (int c = 0; c < 8; ++c) { vv[c] = bf2f(a[c]); vv[8 + c] = bf2f(b[c]); }
#pragma unroll
    for (int r = 0; r < 4; ++r)
#pragma unroll
      for (int c = 0; c < 16; ++c) o[r][c] += p[r][j] * vv[c];
  }

#pragma unroll
  for (int r = 0; r < 4; ++r) {
    float* op = out + gbase + (size_t)(rh * 4 + r) * 1024 + coff;
    f32x4 v0 = {o[r][0], o[r][1], o[r][2], o[r][3]};
    f32x4 v1 = {o[r][4], o[r][5], o[r][6], o[r][7]};
    f32x4 v2 = {o[r][8], o[r][9], o[r][10], o[r][11]};
    f32x4 v3 = {o[r][12], o[r][13], o[r][14], o[r][15]};
    reinterpret_cast<f32x4*>(op)[0] = v0;
    reinterpret_cast<f32x4*>(op)[1] = v1;
    reinterpret_cast<f32x4*>(op)[2] = v2;
    reinterpret_cast<f32x4*>(op)[3] = v3;
  }
}

// ------------------------------------------------------------------- launch
extern "C" void kernel_launch(void* const* d_in, const int* in_sizes, int n_in,
                              void* d_out, int out_size, void* d_ws, size_t ws_size,
                              hipStream_t stream) {
  const float* Xq = (const float*)d_in[0];
  const float* Xk = (const float*)d_in[1];
  const float* Xv = (const float*)d_in[2];
  const float* Wq = (const float*)d_in[3];
  const float* bq = (const float*)d_in[4];
  const float* Wk = (const float*)d_in[5];
  const float* bk = (const float*)d_in[6];
  const float* Wv = (const float*)d_in[7];
  const float* bv = (const float*)d_in[8];

  unsigned short* ws = (unsigned short*)d_ws;
  unsigned short* Wb = ws;                              // 3 x 1M bf16 (6 MB), linear
  unsigned short* QKV = ws + (size_t)3 * 1024 * 1024;   // 3 x 8M bf16 (48 MB)

  cvt_w<<<1536, 256, 0, stream>>>(Wq, Wk, Wv, Wb);
  gemm9<<<768, 512, 0, stream>>>(Xq, Xk, Xv, Wb, bq, bk, bv, QKV);
  attn_kernel<<<512, 256, 0, stream>>>(QKV, (float*)d_out);
}

// Round 10
// 167.572 us; speedup vs baseline: 1.3179x; 1.0042x over previous
//
#include <hip/hip_runtime.h>

// MultiHeadAttention_137438953529 on gfx950.
// B=8, S=1024, E=1024, H=16, D=64.  The reference's reshapes are flat
// reinterpretations => attention mixes only groups of 8 consecutive rows of
// the (8192 x 1024) projected matrices, per 64-wide head slice.
//
// R10: m97-exact GEMM structure (the only one with a verified 874-912 TF
// measurement): BOTH operands staged via global_load_lds, 128x128 tile,
// BK=32, 4 waves, plain 2-barrier __syncthreads loop, ~3 blocks/CU TLP,
// ZERO inline-asm scheduling (no vmcnt, no sched_barrier, no setprio).
// A stays f32 (no cvt_x pass): staged via per-lane-source glds into a
// FRAGMENT-LINEAR LDS layout (each 1KB block = exactly the 64 lanes' 16B
// reads for one (m-frag, f32-half)) -> ds_read addr = uniform + l*16 ->
// conflict-free by construction.  A converts to bf16 at use (cvt_pk under
// MFMA).  B bf16 (cvt_w pre-pass) fragment-linear likewise.
// Kept: XCD-family decode, m97 epilogue, attn kernel.

typedef __attribute__((ext_vector_type(4))) float f32x4;
typedef __attribute__((ext_vector_type(8))) short bf16x8;   // MFMA A/B fragment
typedef __attribute__((ext_vector_type(8))) unsigned short u16x8;

__device__ __forceinline__ unsigned short f2bf(float f) {
  unsigned int u = __builtin_bit_cast(unsigned int, f);
  u += 0x7fffu + ((u >> 16) & 1u);          // round-to-nearest-even
  return (unsigned short)(u >> 16);
}
__device__ __forceinline__ float bf2f(unsigned short b) {
  return __builtin_bit_cast(float, ((unsigned int)b) << 16);
}
__device__ __forceinline__ u16x8 pack8(f32x4 a, f32x4 b) {
  u16x8 o;
  o[0] = f2bf(a[0]); o[1] = f2bf(a[1]); o[2] = f2bf(a[2]); o[3] = f2bf(a[3]);
  o[4] = f2bf(b[0]); o[5] = f2bf(b[1]); o[6] = f2bf(b[2]); o[7] = f2bf(b[3]);
  return o;
}
// 8x f32 -> 8x bf16 via packed cvt (RNE), as MFMA fragment
__device__ __forceinline__ bf16x8 cvt8(f32x4 a, f32x4 b) {
  union { unsigned int u[4]; bf16x8 v; } r;
  asm("v_cvt_pk_bf16_f32 %0, %1, %2" : "=v"(r.u[0]) : "v"(a[0]), "v"(a[1]));
  asm("v_cvt_pk_bf16_f32 %0, %1, %2" : "=v"(r.u[1]) : "v"(a[2]), "v"(a[3]));
  asm("v_cvt_pk_bf16_f32 %0, %1, %2" : "=v"(r.u[2]) : "v"(b[0]), "v"(b[1]));
  asm("v_cvt_pk_bf16_f32 %0, %1, %2" : "=v"(r.u[3]) : "v"(b[2]), "v"(b[3]));
  return r.v;
}

__device__ __forceinline__ void gload_lds16(const void* g, void* l) {
  __builtin_amdgcn_global_load_lds(
      (const __attribute__((address_space(1))) unsigned int*)g,
      (__attribute__((address_space(3))) unsigned int*)l, 16, 0, 0);
}

// --------------------------------------------------- W -> bf16 (linear layout)
__global__ __launch_bounds__(256) void cvt_w(const float* __restrict__ Wq,
                                             const float* __restrict__ Wk,
                                             const float* __restrict__ Wv,
                                             unsigned short* __restrict__ Wb) {
  int i = blockIdx.x * 256 + threadIdx.x;     // 0 .. 393216 (3 * 131072 chunks of 8)
  int proj = i >> 17;
  int local = i & 131071;
  const float* src = (proj == 0 ? Wq : proj == 1 ? Wk : Wv) + (size_t)local * 8;
  f32x4 a = reinterpret_cast<const f32x4*>(src)[0];
  f32x4 b = reinterpret_cast<const f32x4*>(src)[1];
  *reinterpret_cast<u16x8*>(Wb + (size_t)proj * 1048576 + (size_t)local * 8) = pack8(a, b);
}

// ------------------------------------------------------------ QKV projection
// C[8192x1024] = X @ W^T + bias per proj.  BM=BN=128, BK=32, 256 threads,
// 4 waves (2x2), per-wave 64x64 (4x4 frags of 16x16x32 bf16 MFMA), 32 K-iters.
//
// LDS layouts (fragment-linear):
//  Af (f32, 16KB): block bid = mi*2 + sub (mi=row/16 in 0..7, sub = f32-half);
//    lane l of block holds A[mi*16 + (l&15)][(l>>4)*8 + sub*4 .. +4).
//  Bu (bf16, 8KB): block ni in 0..7; lane l holds W-row ni*16+(l&15),
//    k-chunk (l>>4)*8 .. +8.
// glds dest = block_base + l*16 (linear);  source = per-lane address.
__global__ __launch_bounds__(256, 3) void gemm10(
    const float* __restrict__ Xq, const float* __restrict__ Xk, const float* __restrict__ Xv,
    const unsigned short* __restrict__ Wb,
    const float* __restrict__ bq, const float* __restrict__ bk, const float* __restrict__ bv,
    unsigned short* __restrict__ QKV) {
  // XCD-family decode: XCD c (dispatch round-robin d%8) owns x in [8c,8c+8);
  // consecutive-in-time blocks on one XCD share x (X panel L2-resident, read
  // ~once from HBM) and sweep y (W panels cycle; L2+L3 absorb).
  const int d = blockIdx.x;
  const int xcd = d & 7;
  const int k5 = d >> 3;
  const int y = k5 & 7;
  const int rest = k5 >> 3;       // 0..23
  const int proj = rest >> 3;     // 0..2
  const int xg = rest & 7;
  const int x = xcd * 8 + xg;     // 0..63

  const float* X = (proj == 0) ? Xq : (proj == 1) ? Xk : Xv;
  const float* bias = (proj == 0) ? bq : (proj == 1) ? bk : bv;
  const unsigned short* W = Wb + (size_t)proj * 1048576;
  unsigned short* O = QKV + (size_t)proj * 8388608;

  const int rowBase = x * 128;
  const int colBase = y * 128;

  __shared__ alignas(16) float          Af[4096];   // 16 blocks x 64 lanes x 4 f32
  __shared__ alignas(16) unsigned short Bu[4096];   //  8 blocks x 64 lanes x 8 bf16

  const int t = threadIdx.x;
  const int l = t & 63;
  const int w = t >> 6;
  const int wr = w >> 1, wc = w & 1;

  f32x4 acc[4][4];
#pragma unroll
  for (int m = 0; m < 4; ++m)
#pragma unroll
    for (int n = 0; n < 4; ++n) acc[m][n] = f32x4{0.f, 0.f, 0.f, 0.f};

  const int fr = l & 15;          // fragment row within 16
  const int fg = l >> 4;          // fragment k-group (8-elem chunk)

  // ---- staging pointers (advance by BK per iter) ----
  // A rounds j=0..3: bid = j*4 + w; mi = bid>>1; sub = bid&1.
  const float* aSrc[4];
  float* aDst[4];
#pragma unroll
  for (int j = 0; j < 4; ++j) {
    const int bid = j * 4 + w;
    const int mi = bid >> 1, sub = bid & 1;
    aSrc[j] = X + (size_t)(rowBase + mi * 16 + fr) * 1024 + fg * 8 + sub * 4;
    aDst[j] = &Af[bid * 256 + l * 4];
  }
  // B rounds j=0..1: ni = j*4 + w.
  const unsigned short* bSrc[2];
  unsigned short* bDst[2];
#pragma unroll
  for (int j = 0; j < 2; ++j) {
    const int ni = j * 4 + w;
    bSrc[j] = W + (size_t)(colBase + ni * 16 + fr) * 1024 + fg * 8;
    bDst[j] = &Bu[ni * 512 + l * 8];
  }

  // ---- main loop: m97-exact (stage kt, drain at barrier, compute kt) ----
  for (int kt = 0; kt < 32; ++kt) {
    __syncthreads();              // readers done with the buffer
#pragma unroll
    for (int j = 0; j < 4; ++j) { gload_lds16(aSrc[j], aDst[j]); aSrc[j] += 32; }
#pragma unroll
    for (int j = 0; j < 2; ++j) { gload_lds16(bSrc[j], bDst[j]); bSrc[j] += 32; }
    __syncthreads();              // compiler drains vmcnt before the barrier

    bf16x8 af[4], bfr[4];
#pragma unroll
    for (int m = 0; m < 4; ++m) {
      const int mi = wr * 4 + m;
      f32x4 alo = *reinterpret_cast<const f32x4*>(&Af[(mi * 2 + 0) * 256 + l * 4]);
      f32x4 ahi = *reinterpret_cast<const f32x4*>(&Af[(mi * 2 + 1) * 256 + l * 4]);
      af[m] = cvt8(alo, ahi);
    }
#pragma unroll
    for (int n = 0; n < 4; ++n)
      bfr[n] = *reinterpret_cast<const bf16x8*>(&Bu[(wc * 4 + n) * 512 + l * 8]);
#pragma unroll
    for (int m = 0; m < 4; ++m)
#pragma unroll
      for (int n = 0; n < 4; ++n)
        acc[m][n] = __builtin_amdgcn_mfma_f32_16x16x32_bf16(af[m], bfr[n], acc[m][n], 0, 0, 0);
  }

  // ---- epilogue: C/D layout col=lane&15, row=(lane>>4)*4+reg
#pragma unroll
  for (int n = 0; n < 4; ++n) {
    const int col = colBase + wc * 64 + n * 16 + fr;
    const float bn = bias[col];
#pragma unroll
    for (int m = 0; m < 4; ++m) {
      const int row0 = rowBase + wr * 64 + m * 16 + fg * 4;
#pragma unroll
      for (int j = 0; j < 4; ++j)
        O[(size_t)(row0 + j) * 1024 + col] = f2bf(acc[m][n][j] + bn);
    }
  }
}

// ------------------------------------------------------------------ attention
// thread = (n group, head h, d-quarter dq, row-half rh): 4 q-rows x 16 d-cols
// of the 8-key attention; QK partial dots reduced across 4 dq lanes.
__global__ __launch_bounds__(256) void attn_kernel(const unsigned short* __restrict__ QKV,
                                                   float* __restrict__ out) {
  const int t = threadIdx.x;
  const int lane = t & 63;
  const int dq = lane & 3;
  const int h = (lane >> 2) & 15;
  const int rh = (t >> 6) & 1;
  const int n = blockIdx.x * 2 + (t >> 7);

  const unsigned short* Q = QKV;
  const unsigned short* K = QKV + (size_t)8388608;
  const unsigned short* V = QKV + (size_t)16777216;
  const size_t gbase = (size_t)n * 8192;
  const int coff = h * 64 + dq * 16;

  float q[4][16];
#pragma unroll
  for (int r = 0; r < 4; ++r) {
    const unsigned short* qp = Q + gbase + (size_t)(rh * 4 + r) * 1024 + coff;
    u16x8 a = *reinterpret_cast<const u16x8*>(qp);
    u16x8 b = *reinterpret_cast<const u16x8*>(qp + 8);
#pragma unroll
    for (int c = 0; c < 8; ++c) { q[r][c] = bf2f(a[c]); q[r][8 + c] = bf2f(b[c]); }
  }

  float s[4][8];
#pragma unroll
  for (int r = 0; r < 4; ++r)
#pragma unroll
    for (int j = 0; j < 8; ++j) s[r][j] = 0.f;

#pragma unroll
  for (int j = 0; j < 8; ++j) {
    const unsigned short* kp = K + gbase + (size_t)j * 1024 + coff;
    u16x8 a = *reinterpret_cast<const u16x8*>(kp);
    u16x8 b = *reinterpret_cast<const u16x8*>(kp + 8);
    float kv[16];
#pragma unroll
    for (int c = 0; c < 8; ++c) { kv[c] = bf2f(a[c]); kv[8 + c] = bf2f(b[c]); }
#pragma unroll
    for (int r = 0; r < 4; ++r) {
      float acc = 0.f;
#pragma unroll
      for (int c = 0; c < 16; ++c) acc += q[r][c] * kv[c];
      s[r][j] += acc;
    }
  }

#pragma unroll
  for (int r = 0; r < 4; ++r)
#pragma unroll
    for (int j = 0; j < 8; ++j) {
      float v = s[r][j];
      v += __shfl_xor(v, 1, 64);
      v += __shfl_xor(v, 2, 64);
      s[r][j] = v;
    }

  float p[4][8];
#pragma unroll
  for (int r = 0; r < 4; ++r) {
    float mx = s[r][0];
#pragma unroll
    for (int j = 1; j < 8; ++j) mx = fmaxf(mx, s[r][j]);
    float sum = 0.f;
#pragma unroll
    for (int j = 0; j < 8; ++j) {
      float e = __expf(0.125f * (s[r][j] - mx));  // SCALE = 1/sqrt(64)
      p[r][j] = e;
      sum += e;
    }
    float inv = 1.f / sum;
#pragma unroll
    for (int j = 0; j < 8; ++j) p[r][j] *= inv;
  }

  float o[4][16];
#pragma unroll
  for (int r = 0; r < 4; ++r)
#pragma unroll
    for (int c = 0; c < 16; ++c) o[r][c] = 0.f;

#pragma unroll
  for (int j = 0; j < 8; ++j) {
    const unsigned short* vp = V + gbase + (size_t)j * 1024 + coff;
    u16x8 a = *reinterpret_cast<const u16x8*>(vp);
    u16x8 b = *reinterpret_cast<const u16x8*>(vp + 8);
    float vv[16];
#pragma unroll
    for (int c = 0; c < 8; ++c) { vv[c] = bf2f(a[c]); vv[8 + c] = bf2f(b[c]); }
#pragma unroll
    for (int r = 0; r < 4; ++r)
#pragma unroll
      for (int c = 0; c < 16; ++c) o[r][c] += p[r][j] * vv[c];
  }

#pragma unroll
  for (int r = 0; r < 4; ++r) {
    float* op = out + gbase + (size_t)(rh * 4 + r) * 1024 + coff;
    f32x4 v0 = {o[r][0], o[r][1], o[r][2], o[r][3]};
    f32x4 v1 = {o[r][4], o[r][5], o[r][6], o[r][7]};
    f32x4 v2 = {o[r][8], o[r][9], o[r][10], o[r][11]};
    f32x4 v3 = {o[r][12], o[r][13], o[r][14], o[r][15]};
    reinterpret_cast<f32x4*>(op)[0] = v0;
    reinterpret_cast<f32x4*>(op)[1] = v1;
    reinterpret_cast<f32x4*>(op)[2] = v2;
    reinterpret_cast<f32x4*>(op)[3] = v3;
  }
}

// ------------------------------------------------------------------- launch
extern "C" void kernel_launch(void* const* d_in, const int* in_sizes, int n_in,
                              void* d_out, int out_size, void* d_ws, size_t ws_size,
                              hipStream_t stream) {
  const float* Xq = (const float*)d_in[0];
  const float* Xk = (const float*)d_in[1];
  const float* Xv = (const float*)d_in[2];
  const float* Wq = (const float*)d_in[3];
  const float* bq = (const float*)d_in[4];
  const float* Wk = (const float*)d_in[5];
  const float* bk = (const float*)d_in[6];
  const float* Wv = (const float*)d_in[7];
  const float* bv = (const float*)d_in[8];

  unsigned short* ws = (unsigned short*)d_ws;
  unsigned short* Wb = ws;                              // 3 x 1M bf16 (6 MB), linear
  unsigned short* QKV = ws + (size_t)3 * 1024 * 1024;   // 3 x 8M bf16 (48 MB)

  cvt_w<<<1536, 256, 0, stream>>>(Wq, Wk, Wv, Wb);
  gemm10<<<1536, 256, 0, stream>>>(Xq, Xk, Xv, Wb, bq, bk, bv, QKV);
  attn_kernel<<<512, 256, 0, stream>>>(QKV, (float*)d_out);
}

// Round 11
// 148.253 us; speedup vs baseline: 1.4896x; 1.1303x over previous
//
#include <hip/hip_runtime.h>

// MultiHeadAttention_137438953529 on gfx950.
// B=8, S=1024, E=1024, H=16, D=64.  The reference's reshapes are flat
// reinterpretations => attention mixes only groups of 8 consecutive rows of
// the (8192 x 1024) projected matrices, per 64-wide head slice.
//
// R11: champion (R4/R6 dbuf pipeline) with BK=64.  Evidence: depth-3 (R6)
// null, single-buffer (R10) worse -> the binding term is per-fence overhead,
// paid once per K-step.  BK=64 halves fence count and doubles MFMA work per
// fence (32 MFMA ~ 155cy/wave between barriers).  LDS 64KB -> 2 blocks/CU,
// launch_bounds(256,2) (256-reg budget, no R5-style spill).  A: 8xf32x4
// global prefetch (2 iters ahead) -> 16 cvt_pk -> 4 swizzled ds_write_b128
// (chunk XOR c^(r&7), full 32-bank spread).  B: 4 glds, source-side XOR.
// Counted fences: writeA reg-dep drains A(kt+1)+glds(kt); end-of-iter
// vmcnt(8) drains glds(kt+1), leaves A(kt+2) in flight across the barrier.
// Kept verbatim: XCD-family decode, m97 epilogue, cvt_w, attn.

typedef __attribute__((ext_vector_type(4))) float f32x4;
typedef __attribute__((ext_vector_type(8))) short bf16x8;   // MFMA A/B fragment
typedef __attribute__((ext_vector_type(8))) unsigned short u16x8;

#define WAIT_LGKM0 asm volatile("s_waitcnt lgkmcnt(0)" ::: "memory")
#define WAIT_VM(n) asm volatile("s_waitcnt vmcnt(" #n ")" ::: "memory")
#define SCHED0 __builtin_amdgcn_sched_barrier(0)
#define BARRIER __builtin_amdgcn_s_barrier()

__device__ __forceinline__ unsigned short f2bf(float f) {
  unsigned int u = __builtin_bit_cast(unsigned int, f);
  u += 0x7fffu + ((u >> 16) & 1u);          // round-to-nearest-even
  return (unsigned short)(u >> 16);
}
__device__ __forceinline__ float bf2f(unsigned short b) {
  return __builtin_bit_cast(float, ((unsigned int)b) << 16);
}
__device__ __forceinline__ u16x8 pack8(f32x4 a, f32x4 b) {
  u16x8 o;
  o[0] = f2bf(a[0]); o[1] = f2bf(a[1]); o[2] = f2bf(a[2]); o[3] = f2bf(a[3]);
  o[4] = f2bf(b[0]); o[5] = f2bf(b[1]); o[6] = f2bf(b[2]); o[7] = f2bf(b[3]);
  return o;
}
// 8x f32 -> 8x bf16 via packed cvt (RNE)
__device__ __forceinline__ u16x8 cvt8(f32x4 a, f32x4 b) {
  union { unsigned int u[4]; u16x8 v; } r;
  asm("v_cvt_pk_bf16_f32 %0, %1, %2" : "=v"(r.u[0]) : "v"(a[0]), "v"(a[1]));
  asm("v_cvt_pk_bf16_f32 %0, %1, %2" : "=v"(r.u[1]) : "v"(a[2]), "v"(a[3]));
  asm("v_cvt_pk_bf16_f32 %0, %1, %2" : "=v"(r.u[2]) : "v"(b[0]), "v"(b[1]));
  asm("v_cvt_pk_bf16_f32 %0, %1, %2" : "=v"(r.u[3]) : "v"(b[2]), "v"(b[3]));
  return r.v;
}

__device__ __forceinline__ void gload_lds16(const void* g, void* l) {
  __builtin_amdgcn_global_load_lds(
      (const __attribute__((address_space(1))) unsigned int*)g,
      (__attribute__((address_space(3))) unsigned int*)l, 16, 0, 0);
}

// --------------------------------------------------- W -> bf16 (linear layout)
__global__ __launch_bounds__(256) void cvt_w(const float* __restrict__ Wq,
                                             const float* __restrict__ Wk,
                                             const float* __restrict__ Wv,
                                             unsigned short* __restrict__ Wb) {
  int i = blockIdx.x * 256 + threadIdx.x;     // 0 .. 393216 (3 * 131072 chunks of 8)
  int proj = i >> 17;
  int local = i & 131071;
  const float* src = (proj == 0 ? Wq : proj == 1 ? Wk : Wv) + (size_t)local * 8;
  f32x4 a = reinterpret_cast<const f32x4*>(src)[0];
  f32x4 b = reinterpret_cast<const f32x4*>(src)[1];
  *reinterpret_cast<u16x8*>(Wb + (size_t)proj * 1048576 + (size_t)local * 8) = pack8(a, b);
}

// ------------------------------------------------------------ QKV projection
// C[8192x1024] = X @ W^T + bias per proj.  BM=BN=128, BK=64, 256 threads,
// 4 waves (2x2), per-wave 64x64 (4x4 frags x 2 k-halves of 16x16x32 bf16
// MFMA = 32 MFMA per wave per K-tile), 16 K-tiles.
__global__ __launch_bounds__(256, 2) void gemm11(
    const float* __restrict__ Xq, const float* __restrict__ Xk, const float* __restrict__ Xv,
    const unsigned short* __restrict__ Wb,
    const float* __restrict__ bq, const float* __restrict__ bk, const float* __restrict__ bv,
    unsigned short* __restrict__ QKV) {
  // XCD-family decode: XCD c (dispatch round-robin d%8) owns x in [8c,8c+8);
  // consecutive-in-time blocks on one XCD share x (X panel L2-resident, read
  // ~once from HBM) and sweep y (W panels cycle; L2+L3 absorb).
  const int d = blockIdx.x;
  const int xcd = d & 7;
  const int k5 = d >> 3;
  const int y = k5 & 7;
  const int rest = k5 >> 3;       // 0..23
  const int proj = rest >> 3;     // 0..2
  const int xg = rest & 7;
  const int x = xcd * 8 + xg;     // 0..63

  const float* X = (proj == 0) ? Xq : (proj == 1) ? Xk : Xv;
  const float* bias = (proj == 0) ? bq : (proj == 1) ? bk : bv;
  const unsigned short* W = Wb + (size_t)proj * 1048576;
  unsigned short* O = QKV + (size_t)proj * 8388608;

  const int rowBase = x * 128;
  const int colBase = y * 128;

  __shared__ alignas(16) unsigned short As[2][8192];   // [128 rows][64 k], chunk-XOR'd
  __shared__ alignas(16) unsigned short Bs[2][8192];   // [128 rows][64 k], chunk-XOR'd

  const int t = threadIdx.x;
  const int l = t & 63;
  const int w = t >> 6;
  const int wr = w >> 1, wc = w & 1;
  const int fr = l & 15;          // fragment row within 16
  const int fg = l >> 4;          // fragment k-group

  f32x4 acc[4][4];
#pragma unroll
  for (int m = 0; m < 4; ++m)
#pragma unroll
    for (int n = 0; n < 4; ++n) acc[m][n] = f32x4{0.f, 0.f, 0.f, 0.f};

  // fragment read offsets (ushort units): logical 8-elem chunk c of row r
  // lives at physical chunk c ^ (r&7); rows are 64 ushort (128 B).
  int aoff[2][4], boff[2][4];
#pragma unroll
  for (int m = 0; m < 4; ++m) {
    const int ar = wr * 64 + m * 16 + fr;
#pragma unroll
    for (int ks = 0; ks < 2; ++ks)
      aoff[ks][m] = ar * 64 + (((ks * 4 + fg) ^ (ar & 7)) * 8);
  }
#pragma unroll
  for (int n = 0; n < 4; ++n) {
    const int br = wc * 64 + n * 16 + fr;
#pragma unroll
    for (int ks = 0; ks < 2; ++ks)
      boff[ks][n] = br * 64 + (((ks * 4 + fg) ^ (br & 7)) * 8);
  }

  // A issue: thread owns row t>>1, k-half (t&1)*32 -> 8 consecutive f32x4.
  const float* aBase = X + (size_t)(rowBase + (t >> 1)) * 1024 + (t & 1) * 32;
#define ISSUE_A(kt, R)                                                            \
  {                                                                               \
    const f32x4* ap = reinterpret_cast<const f32x4*>(aBase + (kt) * 64);          \
    _Pragma("unroll") for (int i = 0; i < 8; ++i) R[i] = ap[i];                   \
  }

  // A cvt + swizzled ds_write: row r=t>>1, chunks c=h*4+i at phys c^(r&7).
#define WRITE_A(dst, R)                                                           \
  {                                                                               \
    const int r = t >> 1, hh = t & 1;                                             \
    unsigned short* ab = (dst) + r * 64;                                          \
    _Pragma("unroll") for (int i = 0; i < 4; ++i) {                               \
      const int pc = (hh * 4 + i) ^ (r & 7);                                      \
      *reinterpret_cast<u16x8*>(ab + pc * 8) = cvt8(R[2 * i], R[2 * i + 1]);      \
    }                                                                             \
  }

  // B staging: 16 KB via 4 glds/thread.  Linear dest byte o=(j*4+w)*1024+l*16;
  // row=o>>7, phys chunk=(o>>4)&7, source chunk = phys ^ (row&7).
#define STAGE_B(dst, kt)                                                          \
  {                                                                               \
    _Pragma("unroll") for (int j = 0; j < 4; ++j) {                               \
      const int o = (j * 4 + w) * 1024 + l * 16;                                  \
      const int row = o >> 7;                                                     \
      const int sc = ((o >> 4) & 7) ^ (row & 7);                                  \
      gload_lds16(W + (size_t)(colBase + row) * 1024 + (kt) * 64 + sc * 8,        \
                  (char*)(dst) + o);                                              \
    }                                                                             \
  }

#define COMPUTE(buf)                                                              \
  {                                                                               \
    _Pragma("unroll") for (int ks = 0; ks < 2; ++ks) {                            \
      bf16x8 af[4], bfr[4];                                                       \
      _Pragma("unroll") for (int m = 0; m < 4; ++m)                               \
          af[m] = *reinterpret_cast<const bf16x8*>(&As[buf][0] + aoff[ks][m]);    \
      _Pragma("unroll") for (int n = 0; n < 4; ++n)                               \
          bfr[n] = *reinterpret_cast<const bf16x8*>(&Bs[buf][0] + boff[ks][n]);   \
      __builtin_amdgcn_s_setprio(1);                                              \
      _Pragma("unroll") for (int m = 0; m < 4; ++m)                               \
          _Pragma("unroll") for (int n = 0; n < 4; ++n)                           \
              acc[m][n] = __builtin_amdgcn_mfma_f32_16x16x32_bf16(                \
                  af[m], bfr[n], acc[m][n], 0, 0, 0);                             \
      __builtin_amdgcn_s_setprio(0);                                              \
    }                                                                             \
  }

#define FENCE_SEQ SCHED0; BARRIER; SCHED0

  f32x4 aRa[8], aRb[8];

  // ---- prologue: buf0 <- tile 0 (A reg+cvt, B glds); aRa <- A(1) in flight
  ISSUE_A(0, aRa);               // A(0) x8
  STAGE_B(&Bs[0][0], 0);         // glds(0) x4
  WRITE_A(&As[0][0], aRa);       // reg dep: drains A(0), leaves glds(0)
  ISSUE_A(1, aRa);               // A(1) x8 -> [glds(0)4, A(1)8]
  WAIT_LGKM0;
  WAIT_VM(8);                    // drain glds(0); leave A(1)
  FENCE_SEQ;

  // ---- main loop: 16 K-tiles, manual 2-step unroll (static bufs + reg pp)
  for (int kt = 0; kt < 16; kt += 2) {
    // even: compute tile kt (buf0); stage B(kt+1)->buf1; aRb <- A(kt+2);
    //       write A(kt+1)=aRa -> buf1
    {
      STAGE_B(&Bs[1][0], kt + 1);
      if (kt + 2 < 16) ISSUE_A(kt + 2, aRb);
      WRITE_A(&As[1][0], aRa);    // reg dep vmcnt: drains A(kt+1), leaves rest
      COMPUTE(0);
      WAIT_LGKM0;
      if (kt + 2 < 16) { WAIT_VM(8); } else { WAIT_VM(0); }
      FENCE_SEQ;
    }
    // odd: compute tile kt+1 (buf1); stage B(kt+2)->buf0; aRa <- A(kt+3);
    //       write A(kt+2)=aRb -> buf0
    {
      if (kt + 2 < 16) {
        STAGE_B(&Bs[0][0], kt + 2);
        if (kt + 3 < 16) ISSUE_A(kt + 3, aRa);
        WRITE_A(&As[0][0], aRb);
      }
      COMPUTE(1);
      if (kt + 2 < 16) {
        WAIT_LGKM0;
        if (kt + 3 < 16) { WAIT_VM(8); } else { WAIT_VM(0); }
        FENCE_SEQ;
      }
    }
  }

  // ---- epilogue: C/D layout col=lane&15, row=(lane>>4)*4+reg
#pragma unroll
  for (int n = 0; n < 4; ++n) {
    const int col = colBase + wc * 64 + n * 16 + fr;
    const float bn = bias[col];
#pragma unroll
    for (int m = 0; m < 4; ++m) {
      const int row0 = rowBase + wr * 64 + m * 16 + fg * 4;
#pragma unroll
      for (int j = 0; j < 4; ++j)
        O[(size_t)(row0 + j) * 1024 + col] = f2bf(acc[m][n][j] + bn);
    }
  }
#undef ISSUE_A
#undef WRITE_A
#undef STAGE_B
#undef COMPUTE
#undef FENCE_SEQ
}

// ------------------------------------------------------------------ attention
// thread = (n group, head h, d-quarter dq, row-half rh): 4 q-rows x 16 d-cols
// of the 8-key attention; QK partial dots reduced across 4 dq lanes.
__global__ __launch_bounds__(256) void attn_kernel(const unsigned short* __restrict__ QKV,
                                                   float* __restrict__ out) {
  const int t = threadIdx.x;
  const int lane = t & 63;
  const int dq = lane & 3;
  const int h = (lane >> 2) & 15;
  const int rh = (t >> 6) & 1;
  const int n = blockIdx.x * 2 + (t >> 7);

  const unsigned short* Q = QKV;
  const unsigned short* K = QKV + (size_t)8388608;
  const unsigned short* V = QKV + (size_t)16777216;
  const size_t gbase = (size_t)n * 8192;
  const int coff = h * 64 + dq * 16;

  float q[4][16];
#pragma unroll
  for (int r = 0; r < 4; ++r) {
    const unsigned short* qp = Q + gbase + (size_t)(rh * 4 + r) * 1024 + coff;
    u16x8 a = *reinterpret_cast<const u16x8*>(qp);
    u16x8 b = *reinterpret_cast<const u16x8*>(qp + 8);
#pragma unroll
    for (int c = 0; c < 8; ++c) { q[r][c] = bf2f(a[c]); q[r][8 + c] = bf2f(b[c]); }
  }

  float s[4][8];
#pragma unroll
  for (int r = 0; r < 4; ++r)
#pragma unroll
    for (int j = 0; j < 8; ++j) s[r][j] = 0.f;

#pragma unroll
  for (int j = 0; j < 8; ++j) {
    const unsigned short* kp = K + gbase + (size_t)j * 1024 + coff;
    u16x8 a = *reinterpret_cast<const u16x8*>(kp);
    u16x8 b = *reinterpret_cast<const u16x8*>(kp + 8);
    float kv[16];
#pragma unroll
    for (int c = 0; c < 8; ++c) { kv[c] = bf2f(a[c]); kv[8 + c] = bf2f(b[c]); }
#pragma unroll
    for (int r = 0; r < 4; ++r) {
      float acc = 0.f;
#pragma unroll
      for (int c = 0; c < 16; ++c) acc += q[r][c] * kv[c];
      s[r][j] += acc;
    }
  }

#pragma unroll
  for (int r = 0; r < 4; ++r)
#pragma unroll
    for (int j = 0; j < 8; ++j) {
      float v = s[r][j];
      v += __shfl_xor(v, 1, 64);
      v += __shfl_xor(v, 2, 64);
      s[r][j] = v;
    }

  float p[4][8];
#pragma unroll
  for (int r = 0; r < 4; ++r) {
    float mx = s[r][0];
#pragma unroll
    for (int j = 1; j < 8; ++j) mx = fmaxf(mx, s[r][j]);
    float sum = 0.f;
#pragma unroll
    for (int j = 0; j < 8; ++j) {
      float e = __expf(0.125f * (s[r][j] - mx));  // SCALE = 1/sqrt(64)
      p[r][j] = e;
      sum += e;
    }
    float inv = 1.f / sum;
#pragma unroll
    for (int j = 0; j < 8; ++j) p[r][j] *= inv;
  }

  float o[4][16];
#pragma unroll
  for (int r = 0; r < 4; ++r)
#pragma unroll
    for (int c = 0; c < 16; ++c) o[r][c] = 0.f;

#pragma unroll
  for (int j = 0; j < 8; ++j) {
    const unsigned short* vp = V + gbase + (size_t)j * 1024 + coff;
    u16x8 a = *reinterpret_cast<const u16x8*>(vp);
    u16x8 b = *reinterpret_cast<const u16x8*>(vp + 8);
    float vv[16];
#pragma unroll
    for (int c = 0; c < 8; ++c) { vv[c] = bf2f(a[c]); vv[8 + c] = bf2f(b[c]); }
#pragma unroll
    for (int r = 0; r < 4; ++r)
#pragma unroll
      for (int c = 0; c < 16; ++c) o[r][c] += p[r][j] * vv[c];
  }

#pragma unroll
  for (int r = 0; r < 4; ++r) {
    float* op = out + gbase + (size_t)(rh * 4 + r) * 1024 + coff;
    f32x4 v0 = {o[r][0], o[r][1], o[r][2], o[r][3]};
    f32x4 v1 = {o[r][4], o[r][5], o[r][6], o[r][7]};
    f32x4 v2 = {o[r][8], o[r][9], o[r][10], o[r][11]};
    f32x4 v3 = {o[r][12], o[r][13], o[r][14], o[r][15]};
    reinterpret_cast<f32x4*>(op)[0] = v0;
    reinterpret_cast<f32x4*>(op)[1] = v1;
    reinterpret_cast<f32x4*>(op)[2] = v2;
    reinterpret_cast<f32x4*>(op)[3] = v3;
  }
}

// ------------------------------------------------------------------- launch
extern "C" void kernel_launch(void* const* d_in, const int* in_sizes, int n_in,
                              void* d_out, int out_size, void* d_ws, size_t ws_size,
                              hipStream_t stream) {
  const float* Xq = (const float*)d_in[0];
  const float* Xk = (const float*)d_in[1];
  const float* Xv = (const float*)d_in[2];
  const float* Wq = (const float*)d_in[3];
  const float* bq = (const float*)d_in[4];
  const float* Wk = (const float*)d_in[5];
  const float* bk = (const float*)d_in[6];
  const float* Wv = (const float*)d_in[7];
  const float* bv = (const float*)d_in[8];

  unsigned short* ws = (unsigned short*)d_ws;
  unsigned short* Wb = ws;                              // 3 x 1M bf16 (6 MB), linear
  unsigned short* QKV = ws + (size_t)3 * 1024 * 1024;   // 3 x 8M bf16 (48 MB)

  cvt_w<<<1536, 256, 0, stream>>>(Wq, Wk, Wv, Wb);
  gemm11<<<1536, 256, 0, stream>>>(Xq, Xk, Xv, Wb, bq, bk, bv, QKV);
  attn_kernel<<<512, 256, 0, stream>>>(QKV, (float*)d_out);
}